// Round 1
// baseline (3793.573 us; speedup 1.0000x reference)
//
#include <hip/hip_runtime.h>
#include <hip/hip_bf16.h>

#define B_ 4
#define L_ 2048
#define D_ 1024
#define F_ 4096
#define H_ 16
#define E_ 64
#define QB 4

typedef __hip_bfloat16 bf16;
typedef __attribute__((ext_vector_type(8))) short short8;
typedef __attribute__((ext_vector_type(4))) float f32x4;

// ---------------- fp32 -> bf16 convert ----------------
__global__ __launch_bounds__(256) void convert_bf16_kernel(const float* __restrict__ src,
                                                           bf16* __restrict__ dst, int n) {
    int i = (blockIdx.x * 256 + threadIdx.x) * 4;
    if (i + 3 < n) {
        float4 v = *(const float4*)(src + i);
        dst[i + 0] = __float2bfloat16(v.x);
        dst[i + 1] = __float2bfloat16(v.y);
        dst[i + 2] = __float2bfloat16(v.z);
        dst[i + 3] = __float2bfloat16(v.w);
    }
}

// ---------------- attention (fp32) ----------------
// grid: B*H*(L/QB) blocks, 256 threads. Block handles QB query rows of one (b,h).
__global__ __launch_bounds__(256) void attn_kernel(const float* __restrict__ x,
                                                   float* __restrict__ attn_out) {
    __shared__ float qs[QB][E_];        // 1 KB
    __shared__ float sc[QB][L_];        // 32 KB
    __shared__ float red[4];
    __shared__ float inv_l[QB];
    __shared__ float pp[4][QB][E_];     // 4 KB

    const int tid = threadIdx.x;
    const int nqb = L_ / QB;
    const int q0 = (blockIdx.x % nqb) * QB;
    const int bh = blockIdx.x / nqb;
    const int b = bh / H_, h = bh % H_;
    const float* base = x + (size_t)b * L_ * D_ + h * E_;
    const float scale = 0.125f;  // 1/sqrt(64)

    // load Q rows into LDS
    for (int i = tid; i < QB * E_; i += 256) {
        int q = i / E_, e = i % E_;
        qs[q][e] = base[(size_t)(q0 + q) * D_ + e];
    }
    __syncthreads();

    // scores: each thread handles strided s
    for (int s = tid; s < L_; s += 256) {
        const float* krow = base + (size_t)s * D_;
        float acc[QB];
#pragma unroll
        for (int q = 0; q < QB; q++) acc[q] = 0.f;
#pragma unroll 4
        for (int e4 = 0; e4 < E_ / 4; e4++) {
            float4 kv = ((const float4*)krow)[e4];
#pragma unroll
            for (int q = 0; q < QB; q++) {
                float4 qv = ((const float4*)(&qs[q][0]))[e4];
                acc[q] += kv.x * qv.x + kv.y * qv.y + kv.z * qv.z + kv.w * qv.w;
            }
        }
#pragma unroll
        for (int q = 0; q < QB; q++) sc[q][s] = acc[q] * scale;
    }
    __syncthreads();

    // softmax per row
    for (int q = 0; q < QB; q++) {
        float m = -1e30f;
        for (int s = tid; s < L_; s += 256) m = fmaxf(m, sc[q][s]);
#pragma unroll
        for (int o = 32; o > 0; o >>= 1) m = fmaxf(m, __shfl_down(m, o, 64));
        if ((tid & 63) == 0) red[tid >> 6] = m;
        __syncthreads();
        m = fmaxf(fmaxf(red[0], red[1]), fmaxf(red[2], red[3]));
        __syncthreads();
        float l = 0.f;
        for (int s = tid; s < L_; s += 256) {
            float p = __expf(sc[q][s] - m);
            sc[q][s] = p;
            l += p;
        }
#pragma unroll
        for (int o = 32; o > 0; o >>= 1) l += __shfl_down(l, o, 64);
        if ((tid & 63) == 0) red[tid >> 6] = l;
        __syncthreads();
        if (tid == 0) inv_l[q] = 1.0f / (red[0] + red[1] + red[2] + red[3]);
        __syncthreads();
    }

    // A @ V : lane e accumulates over strided s (4 groups)
    const int e = tid & 63, g = tid >> 6;
    float acc[QB];
#pragma unroll
    for (int q = 0; q < QB; q++) acc[q] = 0.f;
    for (int s = g; s < L_; s += 4) {
        float kv = base[(size_t)s * D_ + e];
#pragma unroll
        for (int q = 0; q < QB; q++) acc[q] += sc[q][s] * kv;
    }
#pragma unroll
    for (int q = 0; q < QB; q++) pp[g][q][e] = acc[q];
    __syncthreads();

    // combine 4 partials, scale by 1/l, write out. QB*E_ == 256 == blockDim.
    {
        int q = tid >> 6, ee = tid & 63;
        float v = pp[0][q][ee] + pp[1][q][ee] + pp[2][q][ee] + pp[3][q][ee];
        attn_out[((size_t)b * L_ + q0 + q) * D_ + h * E_ + ee] = v * inv_l[q];
    }
}

// ---------------- residual + layernorm ----------------
// out = LN(a + b) * gamma + beta ; optionally emits bf16 copy
__global__ __launch_bounds__(256) void ln_kernel(const float* __restrict__ A,
                                                 const float* __restrict__ Bres,
                                                 const float* __restrict__ gamma,
                                                 const float* __restrict__ beta,
                                                 float* __restrict__ out_f32,
                                                 bf16* __restrict__ out_bf16) {
    __shared__ float reds[4], reds2[4];
    const int row = blockIdx.x, tid = threadIdx.x;
    const float* pa = A + (size_t)row * D_;
    const float* pb = Bres + (size_t)row * D_;
    float v[4];
    float s = 0.f, s2 = 0.f;
#pragma unroll
    for (int i = 0; i < 4; i++) {
        int c = tid + i * 256;
        float t = pa[c] + pb[c];
        v[i] = t;
        s += t;
        s2 += t * t;
    }
#pragma unroll
    for (int o = 32; o > 0; o >>= 1) {
        s += __shfl_down(s, o, 64);
        s2 += __shfl_down(s2, o, 64);
    }
    if ((tid & 63) == 0) { reds[tid >> 6] = s; reds2[tid >> 6] = s2; }
    __syncthreads();
    s = reds[0] + reds[1] + reds[2] + reds[3];
    s2 = reds2[0] + reds2[1] + reds2[2] + reds2[3];
    float mean = s * (1.0f / D_);
    float var = s2 * (1.0f / D_) - mean * mean;
    float r = rsqrtf(var + 1e-5f);
#pragma unroll
    for (int i = 0; i < 4; i++) {
        int c = tid + i * 256;
        float o = (v[i] - mean) * r * gamma[c] + beta[c];
        if (out_f32) out_f32[(size_t)row * D_ + c] = o;
        if (out_bf16) out_bf16[(size_t)row * D_ + c] = __float2bfloat16(o);
    }
}

// ---------------- bf16 MFMA GEMM, B-transposed ----------------
// C[M][N] = sum_k A[m][k] * Bw[n][k]  (+bias[n]); EPI 0: relu -> bf16 out, EPI 1: fp32 out
// 128x128 tile, BK=32, 256 threads = 4 waves, each wave does 64x64 via 4x4 of 16x16x32.
template <int EPI>
__global__ __launch_bounds__(256) void gemm_bt(const bf16* __restrict__ A,
                                               const bf16* __restrict__ Bw,
                                               const float* __restrict__ bias,
                                               void* __restrict__ Cout,
                                               int M, int N, int K) {
    __shared__ bf16 As[128][40];  // +8 pad: 2-way bank conflicts only (free)
    __shared__ bf16 Bs[128][40];
    const int tid = threadIdx.x;
    const int bm = blockIdx.y, bn = blockIdx.x;
    const int wave = tid >> 6, lane = tid & 63;
    const int wm = (wave >> 1) * 64, wn = (wave & 1) * 64;
    const int lrow = lane & 15, quad = lane >> 4;

    // staging map: thread -> (row, k-chunk); 2 rows per thread for each of A and B
    const int sr = tid >> 2;        // 0..63
    const int sc_ = (tid & 3) * 8;  // 0,8,16,24

    f32x4 acc[4][4];
#pragma unroll
    for (int i = 0; i < 4; i++)
#pragma unroll
        for (int j = 0; j < 4; j++) acc[i][j] = (f32x4){0.f, 0.f, 0.f, 0.f};

    for (int k0 = 0; k0 < K; k0 += 32) {
        __syncthreads();
        // stage A tile (128x32) and B tile (128x32), 16B per load
        *(int4*)(&As[sr][sc_]) = *(const int4*)(A + (size_t)(bm * 128 + sr) * K + k0 + sc_);
        *(int4*)(&As[sr + 64][sc_]) = *(const int4*)(A + (size_t)(bm * 128 + sr + 64) * K + k0 + sc_);
        *(int4*)(&Bs[sr][sc_]) = *(const int4*)(Bw + (size_t)(bn * 128 + sr) * K + k0 + sc_);
        *(int4*)(&Bs[sr + 64][sc_]) = *(const int4*)(Bw + (size_t)(bn * 128 + sr + 64) * K + k0 + sc_);
        __syncthreads();

        short8 af[4], bfg[4];
#pragma unroll
        for (int i = 0; i < 4; i++)
            af[i] = *(const short8*)(&As[wm + i * 16 + lrow][quad * 8]);
#pragma unroll
        for (int j = 0; j < 4; j++)
            bfg[j] = *(const short8*)(&Bs[wn + j * 16 + lrow][quad * 8]);
#pragma unroll
        for (int i = 0; i < 4; i++)
#pragma unroll
            for (int j = 0; j < 4; j++)
                acc[i][j] = __builtin_amdgcn_mfma_f32_16x16x32_bf16(af[i], bfg[j], acc[i][j], 0, 0, 0);
    }

    // epilogue: D mapping col=lane&15, row=quad*4+reg
#pragma unroll
    for (int i = 0; i < 4; i++) {
#pragma unroll
        for (int j = 0; j < 4; j++) {
            int col = bn * 128 + wn + j * 16 + lrow;
            float bv = bias[col];
#pragma unroll
            for (int r = 0; r < 4; r++) {
                int row = bm * 128 + wm + i * 16 + quad * 4 + r;
                float v = acc[i][j][r] + bv;
                if (EPI == 0) {
                    v = fmaxf(v, 0.f);
                    ((bf16*)Cout)[(size_t)row * N + col] = __float2bfloat16(v);
                } else {
                    ((float*)Cout)[(size_t)row * N + col] = v;
                }
            }
        }
    }
}

// ---------------- launch ----------------
extern "C" void kernel_launch(void* const* d_in, const int* in_sizes, int n_in,
                              void* d_out, int out_size, void* d_ws, size_t ws_size,
                              hipStream_t stream) {
    const float* x = (const float*)d_in[0];
    const float* w1 = (const float*)d_in[1];
    const float* b1 = (const float*)d_in[2];
    const float* w2 = (const float*)d_in[3];
    const float* b2 = (const float*)d_in[4];
    const float* g1 = (const float*)d_in[5];
    const float* be1 = (const float*)d_in[6];
    const float* g2 = (const float*)d_in[7];
    const float* be2 = (const float*)d_in[8];
    float* out = (float*)d_out;

    char* ws = (char*)d_ws;
    const size_t MB = 1024 * 1024;
    float* attn_out = (float*)(ws);            // 32 MiB
    float* x1 = (float*)(ws + 32 * MB);        // 32 MiB
    bf16* x1b = (bf16*)(ws + 64 * MB);         // 16 MiB
    bf16* w1b = (bf16*)(ws + 80 * MB);         // 8 MiB
    bf16* w2b = (bf16*)(ws + 88 * MB);         // 8 MiB
    bf16* hb = (bf16*)(ws + 96 * MB);          // 64 MiB  (8192 x 4096 bf16)
    float* y2 = attn_out;                      // reuse (attn_out dead after LN1)

    convert_bf16_kernel<<<4096, 256, 0, stream>>>(w1, w1b, F_ * D_);
    convert_bf16_kernel<<<4096, 256, 0, stream>>>(w2, w2b, D_ * F_);

    attn_kernel<<<B_ * H_ * (L_ / QB), 256, 0, stream>>>(x, attn_out);

    ln_kernel<<<B_ * L_, 256, 0, stream>>>(x, attn_out, g1, be1, x1, x1b);

    gemm_bt<0><<<dim3(F_ / 128, (B_ * L_) / 128), 256, 0, stream>>>(
        x1b, w1b, b1, (void*)hb, B_ * L_, F_, D_);
    gemm_bt<1><<<dim3(D_ / 128, (B_ * L_) / 128), 256, 0, stream>>>(
        hb, w2b, b2, (void*)y2, B_ * L_, D_, F_);

    ln_kernel<<<B_ * L_, 256, 0, stream>>>(x1, y2, g2, be2, out, nullptr);
}

// Round 2
// 545.033 us; speedup vs baseline: 6.9603x; 6.9603x over previous
//
#include <hip/hip_runtime.h>
#include <hip/hip_bf16.h>

#define B_ 4
#define L_ 2048
#define D_ 1024
#define F_ 4096
#define H_ 16
#define E_ 64

typedef __hip_bfloat16 bf16;
typedef __attribute__((ext_vector_type(8))) short short8;
typedef __attribute__((ext_vector_type(4))) float f32x4;

__device__ inline float bf2f(short s) {
    union { unsigned u; float f; } v;
    v.u = ((unsigned)(unsigned short)s) << 16;
    return v.f;
}
__device__ inline short f2bf(float f) {
    union { float f; unsigned u; } v;
    v.f = f;
    unsigned r = (v.u + 0x7fff + ((v.u >> 16) & 1)) >> 16;
    return (short)r;
}

// ---------------- fp32 -> bf16 convert ----------------
__global__ __launch_bounds__(256) void convert_bf16_kernel(const float* __restrict__ src,
                                                           bf16* __restrict__ dst, int n) {
    int i = (blockIdx.x * 256 + threadIdx.x) * 4;
    if (i + 3 < n) {
        float4 v = *(const float4*)(src + i);
        dst[i + 0] = __float2bfloat16(v.x);
        dst[i + 1] = __float2bfloat16(v.y);
        dst[i + 2] = __float2bfloat16(v.z);
        dst[i + 3] = __float2bfloat16(v.w);
    }
}

// ---------------- V^T pre-pass: vt[b][h][e][l] = bf16(x[b][l][h*64+e]) ----------------
__global__ __launch_bounds__(256) void transpose_vt_kernel(const float* __restrict__ x,
                                                           short* __restrict__ vt) {
    __shared__ float tile[64][65];
    const int bh = blockIdx.x, lt = blockIdx.y;
    const int b = bh >> 4, h = bh & 15;
    const int l0 = lt * 64;
    for (int idx = threadIdx.x; idx < 4096; idx += 256) {
        int r = idx >> 6, c = idx & 63;
        tile[r][c] = x[((size_t)b * L_ + l0 + r) * D_ + h * E_ + c];
    }
    __syncthreads();
    for (int idx = threadIdx.x; idx < 4096; idx += 256) {
        int e = idx >> 6, l = idx & 63;
        vt[((size_t)bh * E_ + e) * L_ + l0 + l] = f2bf(tile[l][e]);
    }
}

// ---------------- flash attention, bf16 MFMA ----------------
// grid: (B*H)*16 blocks; block = 256 thr = 4 waves; block handles 128 Q rows of one (b,h).
// Wave w owns Q rows [w*32, w*32+32). S-tiles of 128 iterated with online softmax.
__global__ __launch_bounds__(256, 2) void flash_attn_kernel(const short* __restrict__ xb,
                                                            const short* __restrict__ vt,
                                                            float* __restrict__ attn_out) {
    __shared__ short Ks[128][72];     // [s][e], pitch 144B == 4 banks mod 32
    __shared__ short Vs[64][136];     // [e][s], pitch 272B == 4 banks mod 32
    __shared__ short Ps[4][32][136];  // per-wave P strip

    const int tid = threadIdx.x;
    const int w = tid >> 6, lane = tid & 63;
    const int lrow = lane & 15, quad = lane >> 4;
    const int qt = blockIdx.x & 15;
    const int bh = blockIdx.x >> 4;
    const int b = bh >> 4, h = bh & 15;
    const int q0 = qt * 128;

    const short* xbase = xb + (size_t)b * L_ * D_ + h * E_;

    // Q fragments (A-layout), scale 1/8 folded in (exact: power of 2)
    short8 aq[2][2];
#pragma unroll
    for (int i = 0; i < 2; i++)
#pragma unroll
        for (int kq = 0; kq < 2; kq++) {
            const short* p = xbase + (size_t)(q0 + w * 32 + i * 16 + lrow) * D_ + kq * 32 + quad * 8;
            short8 raw = *(const short8*)p;
            short8 sc;
#pragma unroll
            for (int z = 0; z < 8; z++) sc[z] = f2bf(bf2f(raw[z]) * 0.125f);
            aq[i][kq] = sc;
        }

    float m_st[2][4], l_st[2][4];
    f32x4 acc_o[2][4];
#pragma unroll
    for (int i = 0; i < 2; i++)
#pragma unroll
        for (int r = 0; r < 4; r++) {
            m_st[i][r] = -1e30f;
            l_st[i][r] = 0.f;
        }
#pragma unroll
    for (int i = 0; i < 2; i++)
#pragma unroll
        for (int jo = 0; jo < 4; jo++) acc_o[i][jo] = (f32x4){0.f, 0.f, 0.f, 0.f};

    const int srow = tid >> 1, sseg = (tid & 1) * 32;  // K staging: 2 thr/row
    const int vrow = tid >> 2, vseg = (tid & 3) * 32;  // V staging: 4 thr/row

    for (int s0 = 0; s0 < L_; s0 += 128) {
        __syncthreads();
        {
            const short* ksrc = xbase + (size_t)(s0 + srow) * D_ + sseg;
#pragma unroll
            for (int c = 0; c < 4; c++)
                *(int4*)&Ks[srow][sseg + c * 8] = *(const int4*)(ksrc + c * 8);
            const short* vsrc = vt + ((size_t)bh * E_ + vrow) * L_ + s0 + vseg;
#pragma unroll
            for (int c = 0; c < 4; c++)
                *(int4*)&Vs[vrow][vseg + c * 8] = *(const int4*)(vsrc + c * 8);
        }
        __syncthreads();

        // S = Q K^T  (scaled)
        f32x4 acc_s[2][8];
#pragma unroll
        for (int i = 0; i < 2; i++)
#pragma unroll
            for (int j = 0; j < 8; j++) acc_s[i][j] = (f32x4){0.f, 0.f, 0.f, 0.f};
#pragma unroll
        for (int j = 0; j < 8; j++)
#pragma unroll
            for (int kq = 0; kq < 2; kq++) {
                short8 bk = *(const short8*)&Ks[j * 16 + lrow][kq * 32 + quad * 8];
                acc_s[0][j] = __builtin_amdgcn_mfma_f32_16x16x32_bf16(aq[0][kq], bk, acc_s[0][j], 0, 0, 0);
                acc_s[1][j] = __builtin_amdgcn_mfma_f32_16x16x32_bf16(aq[1][kq], bk, acc_s[1][j], 0, 0, 0);
            }

        // online softmax (rows live on 16-lane groups sharing `quad`)
#pragma unroll
        for (int i = 0; i < 2; i++)
#pragma unroll
            for (int r = 0; r < 4; r++) {
                float mx = acc_s[i][0][r];
#pragma unroll
                for (int j = 1; j < 8; j++) mx = fmaxf(mx, acc_s[i][j][r]);
                mx = fmaxf(mx, __shfl_xor(mx, 1, 64));
                mx = fmaxf(mx, __shfl_xor(mx, 2, 64));
                mx = fmaxf(mx, __shfl_xor(mx, 4, 64));
                mx = fmaxf(mx, __shfl_xor(mx, 8, 64));
                float mn = fmaxf(m_st[i][r], mx);
                float alpha = __expf(m_st[i][r] - mn);
                m_st[i][r] = mn;
                float rs = 0.f;
#pragma unroll
                for (int j = 0; j < 8; j++) {
                    float p = __expf(acc_s[i][j][r] - mn);
                    acc_s[i][j][r] = p;
                    rs += p;
                }
                rs += __shfl_xor(rs, 1, 64);
                rs += __shfl_xor(rs, 2, 64);
                rs += __shfl_xor(rs, 4, 64);
                rs += __shfl_xor(rs, 8, 64);
                l_st[i][r] = l_st[i][r] * alpha + rs;
#pragma unroll
                for (int jo = 0; jo < 4; jo++) {
                    acc_o[i][jo][r] *= alpha;
                }
            }

        // P -> LDS (C-layout scatter), per-wave strip, no barrier needed
#pragma unroll
        for (int i = 0; i < 2; i++)
#pragma unroll
            for (int j = 0; j < 8; j++)
#pragma unroll
                for (int r = 0; r < 4; r++)
                    Ps[w][i * 16 + quad * 4 + r][j * 16 + lrow] = f2bf(acc_s[i][j][r]);

        // O += P V
#pragma unroll
        for (int ks = 0; ks < 4; ks++) {
            short8 ap0 = *(const short8*)&Ps[w][lrow][ks * 32 + quad * 8];
            short8 ap1 = *(const short8*)&Ps[w][16 + lrow][ks * 32 + quad * 8];
#pragma unroll
            for (int jo = 0; jo < 4; jo++) {
                short8 bv = *(const short8*)&Vs[jo * 16 + lrow][ks * 32 + quad * 8];
                acc_o[0][jo] = __builtin_amdgcn_mfma_f32_16x16x32_bf16(ap0, bv, acc_o[0][jo], 0, 0, 0);
                acc_o[1][jo] = __builtin_amdgcn_mfma_f32_16x16x32_bf16(ap1, bv, acc_o[1][jo], 0, 0, 0);
            }
        }
    }

    // epilogue: O /= l
#pragma unroll
    for (int i = 0; i < 2; i++)
#pragma unroll
        for (int r = 0; r < 4; r++) {
            float il = 1.0f / l_st[i][r];
            int row = q0 + w * 32 + i * 16 + quad * 4 + r;
#pragma unroll
            for (int jo = 0; jo < 4; jo++)
                attn_out[((size_t)b * L_ + row) * D_ + h * E_ + jo * 16 + lrow] =
                    acc_o[i][jo][r] * il;
        }
}

// ---------------- residual + layernorm ----------------
__global__ __launch_bounds__(256) void ln_kernel(const float* __restrict__ A,
                                                 const float* __restrict__ Bres,
                                                 const float* __restrict__ gamma,
                                                 const float* __restrict__ beta,
                                                 float* __restrict__ out_f32,
                                                 bf16* __restrict__ out_bf16) {
    __shared__ float reds[4], reds2[4];
    const int row = blockIdx.x, tid = threadIdx.x;
    const float* pa = A + (size_t)row * D_;
    const float* pb = Bres + (size_t)row * D_;
    float v[4];
    float s = 0.f, s2 = 0.f;
#pragma unroll
    for (int i = 0; i < 4; i++) {
        int c = tid + i * 256;
        float t = pa[c] + pb[c];
        v[i] = t;
        s += t;
        s2 += t * t;
    }
#pragma unroll
    for (int o = 32; o > 0; o >>= 1) {
        s += __shfl_down(s, o, 64);
        s2 += __shfl_down(s2, o, 64);
    }
    if ((tid & 63) == 0) { reds[tid >> 6] = s; reds2[tid >> 6] = s2; }
    __syncthreads();
    s = reds[0] + reds[1] + reds[2] + reds[3];
    s2 = reds2[0] + reds2[1] + reds2[2] + reds2[3];
    float mean = s * (1.0f / D_);
    float var = s2 * (1.0f / D_) - mean * mean;
    float r = rsqrtf(var + 1e-5f);
#pragma unroll
    for (int i = 0; i < 4; i++) {
        int c = tid + i * 256;
        float o = (v[i] - mean) * r * gamma[c] + beta[c];
        if (out_f32) out_f32[(size_t)row * D_ + c] = o;
        if (out_bf16) out_bf16[(size_t)row * D_ + c] = __float2bfloat16(o);
    }
}

// ---------------- bf16 MFMA GEMM, B-transposed ----------------
template <int EPI>
__global__ __launch_bounds__(256) void gemm_bt(const bf16* __restrict__ A,
                                               const bf16* __restrict__ Bw,
                                               const float* __restrict__ bias,
                                               void* __restrict__ Cout,
                                               int M, int N, int K) {
    __shared__ bf16 As[128][40];
    __shared__ bf16 Bs[128][40];
    const int tid = threadIdx.x;
    const int bm = blockIdx.y, bn = blockIdx.x;
    const int wave = tid >> 6, lane = tid & 63;
    const int wm = (wave >> 1) * 64, wn = (wave & 1) * 64;
    const int lrow = lane & 15, quad = lane >> 4;

    const int sr = tid >> 2;
    const int sc_ = (tid & 3) * 8;

    f32x4 acc[4][4];
#pragma unroll
    for (int i = 0; i < 4; i++)
#pragma unroll
        for (int j = 0; j < 4; j++) acc[i][j] = (f32x4){0.f, 0.f, 0.f, 0.f};

    for (int k0 = 0; k0 < K; k0 += 32) {
        __syncthreads();
        *(int4*)(&As[sr][sc_]) = *(const int4*)(A + (size_t)(bm * 128 + sr) * K + k0 + sc_);
        *(int4*)(&As[sr + 64][sc_]) = *(const int4*)(A + (size_t)(bm * 128 + sr + 64) * K + k0 + sc_);
        *(int4*)(&Bs[sr][sc_]) = *(const int4*)(Bw + (size_t)(bn * 128 + sr) * K + k0 + sc_);
        *(int4*)(&Bs[sr + 64][sc_]) = *(const int4*)(Bw + (size_t)(bn * 128 + sr + 64) * K + k0 + sc_);
        __syncthreads();

        short8 af[4], bfg[4];
#pragma unroll
        for (int i = 0; i < 4; i++)
            af[i] = *(const short8*)(&As[wm + i * 16 + lrow][quad * 8]);
#pragma unroll
        for (int j = 0; j < 4; j++)
            bfg[j] = *(const short8*)(&Bs[wn + j * 16 + lrow][quad * 8]);
#pragma unroll
        for (int i = 0; i < 4; i++)
#pragma unroll
            for (int j = 0; j < 4; j++)
                acc[i][j] = __builtin_amdgcn_mfma_f32_16x16x32_bf16(af[i], bfg[j], acc[i][j], 0, 0, 0);
    }

#pragma unroll
    for (int i = 0; i < 4; i++) {
#pragma unroll
        for (int j = 0; j < 4; j++) {
            int col = bn * 128 + wn + j * 16 + lrow;
            float bv = bias[col];
#pragma unroll
            for (int r = 0; r < 4; r++) {
                int row = bm * 128 + wm + i * 16 + quad * 4 + r;
                float v = acc[i][j][r] + bv;
                if (EPI == 0) {
                    v = fmaxf(v, 0.f);
                    ((bf16*)Cout)[(size_t)row * N + col] = __float2bfloat16(v);
                } else {
                    ((float*)Cout)[(size_t)row * N + col] = v;
                }
            }
        }
    }
}

// ---------------- launch ----------------
extern "C" void kernel_launch(void* const* d_in, const int* in_sizes, int n_in,
                              void* d_out, int out_size, void* d_ws, size_t ws_size,
                              hipStream_t stream) {
    const float* x = (const float*)d_in[0];
    const float* w1 = (const float*)d_in[1];
    const float* b1 = (const float*)d_in[2];
    const float* w2 = (const float*)d_in[3];
    const float* b2 = (const float*)d_in[4];
    const float* g1 = (const float*)d_in[5];
    const float* be1 = (const float*)d_in[6];
    const float* g2 = (const float*)d_in[7];
    const float* be2 = (const float*)d_in[8];
    float* out = (float*)d_out;

    char* ws = (char*)d_ws;
    const size_t MB = 1024 * 1024;
    float* attn_out = (float*)(ws);            // 32 MiB
    float* x1 = (float*)(ws + 32 * MB);        // 32 MiB
    bf16* x1b = (bf16*)(ws + 64 * MB);         // 16 MiB
    bf16* w1b = (bf16*)(ws + 80 * MB);         // 8 MiB
    bf16* w2b = (bf16*)(ws + 88 * MB);         // 8 MiB
    bf16* hb = (bf16*)(ws + 96 * MB);          // 64 MiB (GEMM phase)
    // attention-phase buffers alias hb's region (dead until gemm1 writes hb):
    short* xb = (short*)(ws + 96 * MB);        // 16 MiB bf16 x
    short* vt = (short*)(ws + 112 * MB);       // 16 MiB bf16 x^T per (b,h)
    float* y2 = attn_out;

    convert_bf16_kernel<<<4096, 256, 0, stream>>>(w1, w1b, F_ * D_);
    convert_bf16_kernel<<<4096, 256, 0, stream>>>(w2, w2b, D_ * F_);
    convert_bf16_kernel<<<8192, 256, 0, stream>>>(x, (bf16*)xb, B_ * L_ * D_);
    transpose_vt_kernel<<<dim3(B_ * H_, L_ / 64), 256, 0, stream>>>(x, vt);

    flash_attn_kernel<<<B_ * H_ * (L_ / 128), 256, 0, stream>>>(xb, vt, attn_out);

    ln_kernel<<<B_ * L_, 256, 0, stream>>>(x, attn_out, g1, be1, x1, x1b);

    gemm_bt<0><<<dim3(F_ / 128, (B_ * L_) / 128), 256, 0, stream>>>(
        x1b, w1b, b1, (void*)hb, B_ * L_, F_, D_);
    gemm_bt<1><<<dim3(D_ / 128, (B_ * L_) / 128), 256, 0, stream>>>(
        hb, w2b, b2, (void*)y2, B_ * L_, D_, F_);

    ln_kernel<<<B_ * L_, 256, 0, stream>>>(x1, y2, g2, be2, out, nullptr);
}

// Round 3
// 443.850 us; speedup vs baseline: 8.5470x; 1.2280x over previous
//
#include <hip/hip_runtime.h>
#include <hip/hip_bf16.h>

#define B_ 4
#define L_ 2048
#define D_ 1024
#define F_ 4096
#define H_ 16
#define E_ 64

typedef __hip_bfloat16 bf16;
typedef __attribute__((ext_vector_type(8))) short short8;
typedef __attribute__((ext_vector_type(4))) float f32x4;

__device__ __forceinline__ short f2bf(float f) {
    union { float f; unsigned u; } v;
    v.f = f;
    unsigned r = (v.u + 0x7fff + ((v.u >> 16) & 1)) >> 16;
    return (short)r;
}

// async global->LDS, 16B per lane, lands at ldsbase + lane*16
__device__ __forceinline__ void gl_lds16(const short* g, short* l) {
    __builtin_amdgcn_global_load_lds((const __attribute__((address_space(1))) void*)g,
                                     (__attribute__((address_space(3))) void*)l, 16, 0, 0);
}

// ---------------- fp32 -> bf16 convert ----------------
__global__ __launch_bounds__(256) void convert_bf16_kernel(const float* __restrict__ src,
                                                           bf16* __restrict__ dst, int n) {
    int i = (blockIdx.x * 256 + threadIdx.x) * 4;
    if (i + 3 < n) {
        float4 v = *(const float4*)(src + i);
        dst[i + 0] = __float2bfloat16(v.x);
        dst[i + 1] = __float2bfloat16(v.y);
        dst[i + 2] = __float2bfloat16(v.z);
        dst[i + 3] = __float2bfloat16(v.w);
    }
}

// ---------------- V^T pre-pass + bf16 x copy ----------------
// vt[b][h][e][l] = bf16(x[b][l][h*64+e]);  xb = bf16(x)
__global__ __launch_bounds__(256) void transpose_vt_kernel(const float* __restrict__ x,
                                                           short* __restrict__ vt,
                                                           short* __restrict__ xb) {
    __shared__ float tile[64][65];
    const int bh = blockIdx.x, lt = blockIdx.y;
    const int b = bh >> 4, h = bh & 15;
    const int l0 = lt * 64;
    for (int idx = threadIdx.x; idx < 4096; idx += 256) {
        int r = idx >> 6, c = idx & 63;
        float v = x[((size_t)b * L_ + l0 + r) * D_ + h * E_ + c];
        tile[r][c] = v;
        xb[((size_t)b * L_ + l0 + r) * D_ + h * E_ + c] = f2bf(v);
    }
    __syncthreads();
    for (int idx = threadIdx.x; idx < 4096; idx += 256) {
        int e = idx >> 6, l = idx & 63;
        vt[((size_t)bh * E_ + e) * L_ + l0 + l] = f2bf(tile[l][e]);
    }
}

// ---------------- flash attention, bf16 MFMA, max-free softmax ----------------
// grid: (B*H)*16 blocks; 256 thr = 4 waves; block = 128 Q rows; S-tile = 64.
__global__ __launch_bounds__(256, 4) void flash_attn_kernel(const float* __restrict__ x,
                                                            const short* __restrict__ xb,
                                                            const short* __restrict__ vt,
                                                            float* __restrict__ attn_out) {
    __shared__ short Ks[64][72];      // [s][e], pitch 36 dw == 4 mod 32
    __shared__ short Vs[64][72];      // [e][s]
    __shared__ short Ps[4][32][72];   // per-wave P strip

    const int tid = threadIdx.x;
    const int w = tid >> 6, lane = tid & 63;
    const int lrow = lane & 15, quad = lane >> 4;
    const int qt = blockIdx.x & 15;
    const int bh = blockIdx.x >> 4;
    const int b = bh >> 4, h = bh & 15;
    const int q0 = qt * 128;

    const short* kbase = xb + (size_t)b * L_ * D_ + h * E_;
    const float* qbase = x + (size_t)b * L_ * D_ + h * E_;

    // Q fragments (A-layout), scale/8 * log2(e) folded into the single bf16 rounding
    const float QS = 0.125f * 1.44269504f;
    short8 aq[2][2];
#pragma unroll
    for (int i = 0; i < 2; i++)
#pragma unroll
        for (int kq = 0; kq < 2; kq++) {
            const float* p = qbase + (size_t)(q0 + w * 32 + i * 16 + lrow) * D_ + kq * 32 + quad * 8;
            float4 v0 = *(const float4*)p;
            float4 v1 = *(const float4*)(p + 4);
            short8 sc;
            sc[0] = f2bf(v0.x * QS); sc[1] = f2bf(v0.y * QS);
            sc[2] = f2bf(v0.z * QS); sc[3] = f2bf(v0.w * QS);
            sc[4] = f2bf(v1.x * QS); sc[5] = f2bf(v1.y * QS);
            sc[6] = f2bf(v1.z * QS); sc[7] = f2bf(v1.w * QS);
            aq[i][kq] = sc;
        }

    float l_st[2][4];
    f32x4 acc_o[2][4];
#pragma unroll
    for (int i = 0; i < 2; i++) {
#pragma unroll
        for (int r = 0; r < 4; r++) l_st[i][r] = 0.f;
#pragma unroll
        for (int jo = 0; jo < 4; jo++) acc_o[i][jo] = (f32x4){0.f, 0.f, 0.f, 0.f};
    }

    const int krow = tid >> 2, kseg = (tid & 3) * 16;  // staging: 4 thr/row, 32 B each

    for (int s0 = 0; s0 < L_; s0 += 64) {
        __syncthreads();
        {
            const short* ks = kbase + (size_t)(s0 + krow) * D_ + kseg;
            *(int4*)&Ks[krow][kseg] = *(const int4*)ks;
            *(int4*)&Ks[krow][kseg + 8] = *(const int4*)(ks + 8);
            const short* vs = vt + ((size_t)bh * E_ + krow) * L_ + s0 + kseg;
            *(int4*)&Vs[krow][kseg] = *(const int4*)vs;
            *(int4*)&Vs[krow][kseg + 8] = *(const int4*)(vs + 8);
        }
        __syncthreads();

        // S' = (Q*scale*log2e) K^T
        f32x4 acc_s[2][4];
#pragma unroll
        for (int i = 0; i < 2; i++)
#pragma unroll
            for (int j = 0; j < 4; j++) acc_s[i][j] = (f32x4){0.f, 0.f, 0.f, 0.f};
#pragma unroll
        for (int j = 0; j < 4; j++)
#pragma unroll
            for (int kq = 0; kq < 2; kq++) {
                short8 bk = *(const short8*)&Ks[j * 16 + lrow][kq * 32 + quad * 8];
                acc_s[0][j] = __builtin_amdgcn_mfma_f32_16x16x32_bf16(aq[0][kq], bk, acc_s[0][j], 0, 0, 0);
                acc_s[1][j] = __builtin_amdgcn_mfma_f32_16x16x32_bf16(aq[1][kq], bk, acc_s[1][j], 0, 0, 0);
            }

        // P = exp2(S'), per-lane partial row sums, scatter to LDS (round-half-up bf16)
#pragma unroll
        for (int i = 0; i < 2; i++)
#pragma unroll
            for (int j = 0; j < 4; j++)
#pragma unroll
                for (int r = 0; r < 4; r++) {
                    float p = __builtin_amdgcn_exp2f(acc_s[i][j][r]);
                    l_st[i][r] += p;
                    unsigned u = __float_as_uint(p);
                    Ps[w][i * 16 + quad * 4 + r][j * 16 + lrow] = (short)((u + 0x8000) >> 16);
                }

        // O += P V
#pragma unroll
        for (int ks = 0; ks < 2; ks++) {
            short8 ap0 = *(const short8*)&Ps[w][lrow][ks * 32 + quad * 8];
            short8 ap1 = *(const short8*)&Ps[w][16 + lrow][ks * 32 + quad * 8];
#pragma unroll
            for (int jo = 0; jo < 4; jo++) {
                short8 bv = *(const short8*)&Vs[jo * 16 + lrow][ks * 32 + quad * 8];
                acc_o[0][jo] = __builtin_amdgcn_mfma_f32_16x16x32_bf16(ap0, bv, acc_o[0][jo], 0, 0, 0);
                acc_o[1][jo] = __builtin_amdgcn_mfma_f32_16x16x32_bf16(ap1, bv, acc_o[1][jo], 0, 0, 0);
            }
        }
    }

    // epilogue: reduce l across the 16 column-lanes, then O /= l
#pragma unroll
    for (int i = 0; i < 2; i++)
#pragma unroll
        for (int r = 0; r < 4; r++) {
            float l = l_st[i][r];
            l += __shfl_xor(l, 1, 64);
            l += __shfl_xor(l, 2, 64);
            l += __shfl_xor(l, 4, 64);
            l += __shfl_xor(l, 8, 64);
            float il = 1.0f / l;
            int row = q0 + w * 32 + i * 16 + quad * 4 + r;
#pragma unroll
            for (int jo = 0; jo < 4; jo++)
                attn_out[((size_t)b * L_ + row) * D_ + h * E_ + jo * 16 + lrow] =
                    acc_o[i][jo][r] * il;
        }
}

// ---------------- residual + layernorm ----------------
__global__ __launch_bounds__(256) void ln_kernel(const float* __restrict__ A,
                                                 const float* __restrict__ Bres,
                                                 const float* __restrict__ gamma,
                                                 const float* __restrict__ beta,
                                                 float* __restrict__ out_f32,
                                                 bf16* __restrict__ out_bf16) {
    __shared__ float reds[4], reds2[4];
    const int row = blockIdx.x, tid = threadIdx.x;
    const float* pa = A + (size_t)row * D_;
    const float* pb = Bres + (size_t)row * D_;
    float v[4];
    float s = 0.f, s2 = 0.f;
#pragma unroll
    for (int i = 0; i < 4; i++) {
        int c = tid + i * 256;
        float t = pa[c] + pb[c];
        v[i] = t;
        s += t;
        s2 += t * t;
    }
#pragma unroll
    for (int o = 32; o > 0; o >>= 1) {
        s += __shfl_down(s, o, 64);
        s2 += __shfl_down(s2, o, 64);
    }
    if ((tid & 63) == 0) { reds[tid >> 6] = s; reds2[tid >> 6] = s2; }
    __syncthreads();
    s = reds[0] + reds[1] + reds[2] + reds[3];
    s2 = reds2[0] + reds2[1] + reds2[2] + reds2[3];
    float mean = s * (1.0f / D_);
    float var = s2 * (1.0f / D_) - mean * mean;
    float r = rsqrtf(var + 1e-5f);
#pragma unroll
    for (int i = 0; i < 4; i++) {
        int c = tid + i * 256;
        float o = (v[i] - mean) * r * gamma[c] + beta[c];
        if (out_f32) out_f32[(size_t)row * D_ + c] = o;
        if (out_bf16) out_bf16[(size_t)row * D_ + c] = __float2bfloat16(o);
    }
}

// ---------------- bf16 MFMA GEMM, B-transposed, global_load_lds + XOR swizzle ----------------
// C[M][N] = sum_k A[m][k]*Bw[n][k] (+bias); EPI 0: relu->bf16, EPI 1: fp32.
// LDS layout: row r, chunk c (8 shorts) holds global chunk c ^ ((r>>1)&3).
template <int EPI>
__global__ __launch_bounds__(256, 2) void gemm_bt(const bf16* __restrict__ A,
                                                  const bf16* __restrict__ Bw,
                                                  const float* __restrict__ bias,
                                                  void* __restrict__ Cout,
                                                  int M, int N, int K) {
    __shared__ short As[128 * 32];
    __shared__ short Bs[128 * 32];
    const int tid = threadIdx.x;
    const int bm = blockIdx.y, bn = blockIdx.x;
    const int wave = tid >> 6, lane = tid & 63;
    const int wm = (wave >> 1) * 64, wn = (wave & 1) * 64;
    const int lrow = lane & 15, quad = lane >> 4;

    const int cg = ((lane & 3) ^ ((lane >> 3) & 3)) * 8;   // swizzled fetch chunk (shorts)
    const int rsub = lane >> 2;                            // row within 16-row DMA group
    const int rchunk = (quad ^ ((lrow >> 1) & 3)) * 8;     // swizzled read chunk (shorts)

    const short* Ag = (const short*)A;
    const short* Bg = (const short*)Bw;

    f32x4 acc[4][4];
#pragma unroll
    for (int i = 0; i < 4; i++)
#pragma unroll
        for (int j = 0; j < 4; j++) acc[i][j] = (f32x4){0.f, 0.f, 0.f, 0.f};

    for (int k0 = 0; k0 < K; k0 += 32) {
        __syncthreads();
#pragma unroll
        for (int t = 0; t < 2; t++) {
            int rt = wave * 32 + t * 16;  // tile-row base of this DMA group
            gl_lds16(Ag + (size_t)(bm * 128 + rt + rsub) * K + k0 + cg, &As[rt * 32]);
            gl_lds16(Bg + (size_t)(bn * 128 + rt + rsub) * K + k0 + cg, &Bs[rt * 32]);
        }
        __syncthreads();

        short8 af[4], bfg[4];
#pragma unroll
        for (int i = 0; i < 4; i++)
            af[i] = *(const short8*)&As[(wm + i * 16 + lrow) * 32 + rchunk];
#pragma unroll
        for (int j = 0; j < 4; j++)
            bfg[j] = *(const short8*)&Bs[(wn + j * 16 + lrow) * 32 + rchunk];
#pragma unroll
        for (int i = 0; i < 4; i++)
#pragma unroll
            for (int j = 0; j < 4; j++)
                acc[i][j] = __builtin_amdgcn_mfma_f32_16x16x32_bf16(af[i], bfg[j], acc[i][j], 0, 0, 0);
    }

#pragma unroll
    for (int i = 0; i < 4; i++) {
#pragma unroll
        for (int j = 0; j < 4; j++) {
            int col = bn * 128 + wn + j * 16 + lrow;
            float bv = bias[col];
#pragma unroll
            for (int r = 0; r < 4; r++) {
                int row = bm * 128 + wm + i * 16 + quad * 4 + r;
                float v = acc[i][j][r] + bv;
                if (EPI == 0) {
                    v = fmaxf(v, 0.f);
                    ((bf16*)Cout)[(size_t)row * N + col] = __float2bfloat16(v);
                } else {
                    ((float*)Cout)[(size_t)row * N + col] = v;
                }
            }
        }
    }
}

// ---------------- launch ----------------
extern "C" void kernel_launch(void* const* d_in, const int* in_sizes, int n_in,
                              void* d_out, int out_size, void* d_ws, size_t ws_size,
                              hipStream_t stream) {
    const float* x = (const float*)d_in[0];
    const float* w1 = (const float*)d_in[1];
    const float* b1 = (const float*)d_in[2];
    const float* w2 = (const float*)d_in[3];
    const float* b2 = (const float*)d_in[4];
    const float* g1 = (const float*)d_in[5];
    const float* be1 = (const float*)d_in[6];
    const float* g2 = (const float*)d_in[7];
    const float* be2 = (const float*)d_in[8];
    float* out = (float*)d_out;

    char* ws = (char*)d_ws;
    const size_t MB = 1024 * 1024;
    float* attn_out = (float*)(ws);            // 32 MiB
    float* x1 = (float*)(ws + 32 * MB);        // 32 MiB
    bf16* x1b = (bf16*)(ws + 64 * MB);         // 16 MiB
    bf16* w1b = (bf16*)(ws + 80 * MB);         // 8 MiB
    bf16* w2b = (bf16*)(ws + 88 * MB);         // 8 MiB
    bf16* hb = (bf16*)(ws + 96 * MB);          // 64 MiB (GEMM phase)
    // attention-phase buffers alias hb's region (dead until gemm1 writes hb):
    short* xb = (short*)(ws + 96 * MB);        // 16 MiB bf16 x
    short* vt = (short*)(ws + 112 * MB);       // 16 MiB bf16 x^T per (b,h)
    float* y2 = attn_out;

    convert_bf16_kernel<<<4096, 256, 0, stream>>>(w1, w1b, F_ * D_);
    convert_bf16_kernel<<<4096, 256, 0, stream>>>(w2, w2b, D_ * F_);
    transpose_vt_kernel<<<dim3(B_ * H_, L_ / 64), 256, 0, stream>>>(x, vt, xb);

    flash_attn_kernel<<<B_ * H_ * (L_ / 128), 256, 0, stream>>>(x, xb, vt, attn_out);

    ln_kernel<<<B_ * L_, 256, 0, stream>>>(x, attn_out, g1, be1, x1, x1b);

    gemm_bt<0><<<dim3(F_ / 128, (B_ * L_) / 128), 256, 0, stream>>>(
        x1b, w1b, b1, (void*)hb, B_ * L_, F_, D_);
    gemm_bt<1><<<dim3(D_ / 128, (B_ * L_) / 128), 256, 0, stream>>>(
        hb, w2b, b2, (void*)y2, B_ * L_, D_, F_);

    ln_kernel<<<B_ * L_, 256, 0, stream>>>(x1, y2, g2, be2, out, nullptr);
}

// Round 4
// 438.692 us; speedup vs baseline: 8.6475x; 1.0118x over previous
//
#include <hip/hip_runtime.h>
#include <hip/hip_bf16.h>

#define B_ 4
#define L_ 2048
#define D_ 1024
#define F_ 4096
#define H_ 16
#define E_ 64

typedef __hip_bfloat16 bf16;
typedef __attribute__((ext_vector_type(8))) short short8;
typedef __attribute__((ext_vector_type(4))) float f32x4;

__device__ __forceinline__ short f2bf(float f) {
    union { float f; unsigned u; } v;
    v.f = f;
    unsigned r = (v.u + 0x7fff + ((v.u >> 16) & 1)) >> 16;
    return (short)r;
}

// async global->LDS, 16B per lane, lands at ldsbase + lane*16
__device__ __forceinline__ void gl_lds16(const short* g, short* l) {
    __builtin_amdgcn_global_load_lds((const __attribute__((address_space(1))) void*)g,
                                     (__attribute__((address_space(3))) void*)l, 16, 0, 0);
}

// ---------------- fp32 -> bf16 convert ----------------
__global__ __launch_bounds__(256) void convert_bf16_kernel(const float* __restrict__ src,
                                                           bf16* __restrict__ dst, int n) {
    int i = (blockIdx.x * 256 + threadIdx.x) * 4;
    if (i + 3 < n) {
        float4 v = *(const float4*)(src + i);
        dst[i + 0] = __float2bfloat16(v.x);
        dst[i + 1] = __float2bfloat16(v.y);
        dst[i + 2] = __float2bfloat16(v.z);
        dst[i + 3] = __float2bfloat16(v.w);
    }
}

// ---------------- V^T pre-pass + bf16 x copy ----------------
__global__ __launch_bounds__(256) void transpose_vt_kernel(const float* __restrict__ x,
                                                           short* __restrict__ vt,
                                                           short* __restrict__ xb) {
    __shared__ float tile[64][65];
    const int bh = blockIdx.x, lt = blockIdx.y;
    const int b = bh >> 4, h = bh & 15;
    const int l0 = lt * 64;
    for (int idx = threadIdx.x; idx < 4096; idx += 256) {
        int r = idx >> 6, c = idx & 63;
        float v = x[((size_t)b * L_ + l0 + r) * D_ + h * E_ + c];
        tile[r][c] = v;
        xb[((size_t)b * L_ + l0 + r) * D_ + h * E_ + c] = f2bf(v);
    }
    __syncthreads();
    for (int idx = threadIdx.x; idx < 4096; idx += 256) {
        int e = idx >> 6, l = idx & 63;
        vt[((size_t)bh * E_ + e) * L_ + l0 + l] = f2bf(tile[l][e]);
    }
}

// ---------------- flash attention, bf16 MFMA, max-free softmax ----------------
// grid: (B*H)*16 blocks; 256 thr = 4 waves; block = 128 Q rows; S-tile = 64.
__global__ __launch_bounds__(256, 4) void flash_attn_kernel(const float* __restrict__ x,
                                                            const short* __restrict__ xb,
                                                            const short* __restrict__ vt,
                                                            float* __restrict__ attn_out) {
    __shared__ short Ks[64][72];      // [s][e]
    __shared__ short Vs[64][72];      // [e][s]
    __shared__ short Ps[4][32][68];   // per-wave P strip; pitch 34 dw -> conflict-free scatter

    const int tid = threadIdx.x;
    const int w = tid >> 6, lane = tid & 63;
    const int lrow = lane & 15, quad = lane >> 4;
    const int qt = blockIdx.x & 15;
    const int bh = blockIdx.x >> 4;
    const int b = bh >> 4, h = bh & 15;
    const int q0 = qt * 128;

    const short* kbase = xb + (size_t)b * L_ * D_ + h * E_;
    const float* qbase = x + (size_t)b * L_ * D_ + h * E_;

    // Q fragments (A-layout), scale/8 * log2(e) folded into the single bf16 rounding
    const float QS = 0.125f * 1.44269504f;
    short8 aq[2][2];
#pragma unroll
    for (int i = 0; i < 2; i++)
#pragma unroll
        for (int kq = 0; kq < 2; kq++) {
            const float* p = qbase + (size_t)(q0 + w * 32 + i * 16 + lrow) * D_ + kq * 32 + quad * 8;
            float4 v0 = *(const float4*)p;
            float4 v1 = *(const float4*)(p + 4);
            short8 sc;
            sc[0] = f2bf(v0.x * QS); sc[1] = f2bf(v0.y * QS);
            sc[2] = f2bf(v0.z * QS); sc[3] = f2bf(v0.w * QS);
            sc[4] = f2bf(v1.x * QS); sc[5] = f2bf(v1.y * QS);
            sc[6] = f2bf(v1.z * QS); sc[7] = f2bf(v1.w * QS);
            aq[i][kq] = sc;
        }

    // ones B-fragment for the l-sum MFMA (bf16 1.0 = 0x3F80)
    short8 ones;
#pragma unroll
    for (int z = 0; z < 8; z++) ones[z] = (short)0x3F80;

    f32x4 acc_o[2][4];
    f32x4 acc_l[2];
#pragma unroll
    for (int i = 0; i < 2; i++) {
        acc_l[i] = (f32x4){0.f, 0.f, 0.f, 0.f};
#pragma unroll
        for (int jo = 0; jo < 4; jo++) acc_o[i][jo] = (f32x4){0.f, 0.f, 0.f, 0.f};
    }

    const int krow = tid >> 2, kseg = (tid & 3) * 16;  // staging: 4 thr/row, 32 B each

    for (int s0 = 0; s0 < L_; s0 += 64) {
        __syncthreads();
        {
            const short* ks = kbase + (size_t)(s0 + krow) * D_ + kseg;
            *(int4*)&Ks[krow][kseg] = *(const int4*)ks;
            *(int4*)&Ks[krow][kseg + 8] = *(const int4*)(ks + 8);
            const short* vs = vt + ((size_t)bh * E_ + krow) * L_ + s0 + kseg;
            *(int4*)&Vs[krow][kseg] = *(const int4*)vs;
            *(int4*)&Vs[krow][kseg + 8] = *(const int4*)(vs + 8);
        }
        __syncthreads();

        // S' = (Q*scale*log2e) K^T
        f32x4 acc_s[2][4];
#pragma unroll
        for (int i = 0; i < 2; i++)
#pragma unroll
            for (int j = 0; j < 4; j++) acc_s[i][j] = (f32x4){0.f, 0.f, 0.f, 0.f};
#pragma unroll
        for (int j = 0; j < 4; j++)
#pragma unroll
            for (int kq = 0; kq < 2; kq++) {
                short8 bk = *(const short8*)&Ks[j * 16 + lrow][kq * 32 + quad * 8];
                acc_s[0][j] = __builtin_amdgcn_mfma_f32_16x16x32_bf16(aq[0][kq], bk, acc_s[0][j], 0, 0, 0);
                acc_s[1][j] = __builtin_amdgcn_mfma_f32_16x16x32_bf16(aq[1][kq], bk, acc_s[1][j], 0, 0, 0);
            }

        // P = exp2(S'), scatter to LDS (round-half-up bf16); l-sum comes from MFMA below
#pragma unroll
        for (int i = 0; i < 2; i++)
#pragma unroll
            for (int j = 0; j < 4; j++)
#pragma unroll
                for (int r = 0; r < 4; r++) {
                    float p = __builtin_amdgcn_exp2f(acc_s[i][j][r]);
                    unsigned u = __float_as_uint(p);
                    Ps[w][i * 16 + quad * 4 + r][j * 16 + lrow] = (short)((u + 0x8000) >> 16);
                }

        // O += P V ;  l += P * 1
#pragma unroll
        for (int ks = 0; ks < 2; ks++) {
            short8 ap0 = *(const short8*)&Ps[w][lrow][ks * 32 + quad * 8];
            short8 ap1 = *(const short8*)&Ps[w][16 + lrow][ks * 32 + quad * 8];
            acc_l[0] = __builtin_amdgcn_mfma_f32_16x16x32_bf16(ap0, ones, acc_l[0], 0, 0, 0);
            acc_l[1] = __builtin_amdgcn_mfma_f32_16x16x32_bf16(ap1, ones, acc_l[1], 0, 0, 0);
#pragma unroll
            for (int jo = 0; jo < 4; jo++) {
                short8 bv = *(const short8*)&Vs[jo * 16 + lrow][ks * 32 + quad * 8];
                acc_o[0][jo] = __builtin_amdgcn_mfma_f32_16x16x32_bf16(ap0, bv, acc_o[0][jo], 0, 0, 0);
                acc_o[1][jo] = __builtin_amdgcn_mfma_f32_16x16x32_bf16(ap1, bv, acc_o[1][jo], 0, 0, 0);
            }
        }
    }

    // epilogue: O /= l  (l already reduced by the ones-MFMA, same value in every col)
#pragma unroll
    for (int i = 0; i < 2; i++)
#pragma unroll
        for (int r = 0; r < 4; r++) {
            float il = 1.0f / acc_l[i][r];
            int row = q0 + w * 32 + i * 16 + quad * 4 + r;
#pragma unroll
            for (int jo = 0; jo < 4; jo++)
                attn_out[((size_t)b * L_ + row) * D_ + h * E_ + jo * 16 + lrow] =
                    acc_o[i][jo][r] * il;
        }
}

// ---------------- residual + layernorm (vectorized), optional second input ----------------
__global__ __launch_bounds__(256) void ln_kernel(const float* __restrict__ A,
                                                 const float* __restrict__ Bres,
                                                 const float* __restrict__ gamma,
                                                 const float* __restrict__ beta,
                                                 float* __restrict__ out_f32,
                                                 bf16* __restrict__ out_bf16) {
    __shared__ float reds[4], reds2[4];
    const int row = blockIdx.x, tid = threadIdx.x;
    const int c4 = tid * 4;
    float4 va = *(const float4*)(A + (size_t)row * D_ + c4);
    if (Bres) {
        float4 vb = *(const float4*)(Bres + (size_t)row * D_ + c4);
        va.x += vb.x; va.y += vb.y; va.z += vb.z; va.w += vb.w;
    }
    float s = va.x + va.y + va.z + va.w;
    float s2 = va.x * va.x + va.y * va.y + va.z * va.z + va.w * va.w;
#pragma unroll
    for (int o = 32; o > 0; o >>= 1) {
        s += __shfl_down(s, o, 64);
        s2 += __shfl_down(s2, o, 64);
    }
    if ((tid & 63) == 0) { reds[tid >> 6] = s; reds2[tid >> 6] = s2; }
    __syncthreads();
    s = reds[0] + reds[1] + reds[2] + reds[3];
    s2 = reds2[0] + reds2[1] + reds2[2] + reds2[3];
    float mean = s * (1.0f / D_);
    float var = s2 * (1.0f / D_) - mean * mean;
    float r = rsqrtf(var + 1e-5f);
    float4 vg = *(const float4*)(gamma + c4);
    float4 vbt = *(const float4*)(beta + c4);
    float4 o;
    o.x = (va.x - mean) * r * vg.x + vbt.x;
    o.y = (va.y - mean) * r * vg.y + vbt.y;
    o.z = (va.z - mean) * r * vg.z + vbt.z;
    o.w = (va.w - mean) * r * vg.w + vbt.w;
    if (out_f32) *(float4*)(out_f32 + (size_t)row * D_ + c4) = o;
    if (out_bf16) {
        unsigned p0 = ((unsigned)(unsigned short)f2bf(o.x)) | (((unsigned)(unsigned short)f2bf(o.y)) << 16);
        unsigned p1 = ((unsigned)(unsigned short)f2bf(o.z)) | (((unsigned)(unsigned short)f2bf(o.w)) << 16);
        int2 pk = make_int2((int)p0, (int)p1);
        *(int2*)((short*)out_bf16 + (size_t)row * D_ + c4) = pk;
    }
}

// ---------------- bf16 MFMA GEMM, B-transposed, m97 structure ----------------
// C[M][N] = sum_k A[m][k]*Bw[n][k] (+bias)
// EPI 0: relu -> bf16 out;  EPI 1: fp32 out;  EPI 2: fp32 out + residual RES
template <int EPI>
__global__ __launch_bounds__(256, 3) void gemm_bt(const bf16* __restrict__ A,
                                                  const bf16* __restrict__ Bw,
                                                  const float* __restrict__ bias,
                                                  const float* __restrict__ RES,
                                                  void* __restrict__ Cout,
                                                  int M, int N, int K) {
    __shared__ short As[128 * 32];
    __shared__ short Bs[128 * 32];
    const int tid = threadIdx.x;
    const int bm = blockIdx.y, bn = blockIdx.x;
    const int wave = tid >> 6, lane = tid & 63;
    const int wm = (wave >> 1) * 64, wn = (wave & 1) * 64;
    const int lrow = lane & 15, quad = lane >> 4;

    const int cg = (lane & 3) * 8;   // fetch chunk (shorts) — identity layout (m97)
    const int rsub = lane >> 2;      // row within 16-row DMA group

    const short* Ag = (const short*)A;
    const short* Bg = (const short*)Bw;

    f32x4 acc[4][4];
#pragma unroll
    for (int i = 0; i < 4; i++)
#pragma unroll
        for (int j = 0; j < 4; j++) acc[i][j] = (f32x4){0.f, 0.f, 0.f, 0.f};

    for (int k0 = 0; k0 < K; k0 += 32) {
        __syncthreads();
#pragma unroll
        for (int t = 0; t < 2; t++) {
            int rt = wave * 32 + t * 16;
            gl_lds16(Ag + (size_t)(bm * 128 + rt + rsub) * K + k0 + cg, &As[rt * 32]);
            gl_lds16(Bg + (size_t)(bn * 128 + rt + rsub) * K + k0 + cg, &Bs[rt * 32]);
        }
        __syncthreads();

        short8 af[4], bfg[4];
#pragma unroll
        for (int i = 0; i < 4; i++)
            af[i] = *(const short8*)&As[(wm + i * 16 + lrow) * 32 + quad * 8];
#pragma unroll
        for (int j = 0; j < 4; j++)
            bfg[j] = *(const short8*)&Bs[(wn + j * 16 + lrow) * 32 + quad * 8];
#pragma unroll
        for (int i = 0; i < 4; i++)
#pragma unroll
            for (int j = 0; j < 4; j++)
                acc[i][j] = __builtin_amdgcn_mfma_f32_16x16x32_bf16(af[i], bfg[j], acc[i][j], 0, 0, 0);
    }

#pragma unroll
    for (int i = 0; i < 4; i++) {
#pragma unroll
        for (int j = 0; j < 4; j++) {
            int col = bn * 128 + wn + j * 16 + lrow;
            float bv = bias[col];
#pragma unroll
            for (int r = 0; r < 4; r++) {
                int row = bm * 128 + wm + i * 16 + quad * 4 + r;
                float v = acc[i][j][r] + bv;
                if (EPI == 0) {
                    v = fmaxf(v, 0.f);
                    ((bf16*)Cout)[(size_t)row * N + col] = __float2bfloat16(v);
                } else if (EPI == 1) {
                    ((float*)Cout)[(size_t)row * N + col] = v;
                } else {
                    v += RES[(size_t)row * N + col];
                    ((float*)Cout)[(size_t)row * N + col] = v;
                }
            }
        }
    }
}

// ---------------- launch ----------------
extern "C" void kernel_launch(void* const* d_in, const int* in_sizes, int n_in,
                              void* d_out, int out_size, void* d_ws, size_t ws_size,
                              hipStream_t stream) {
    const float* x = (const float*)d_in[0];
    const float* w1 = (const float*)d_in[1];
    const float* b1 = (const float*)d_in[2];
    const float* w2 = (const float*)d_in[3];
    const float* b2 = (const float*)d_in[4];
    const float* g1 = (const float*)d_in[5];
    const float* be1 = (const float*)d_in[6];
    const float* g2 = (const float*)d_in[7];
    const float* be2 = (const float*)d_in[8];
    float* out = (float*)d_out;

    char* ws = (char*)d_ws;
    const size_t MB = 1024 * 1024;
    float* attn_out = (float*)(ws);            // 32 MiB
    float* x1 = (float*)(ws + 32 * MB);        // 32 MiB
    bf16* x1b = (bf16*)(ws + 64 * MB);         // 16 MiB
    bf16* w1b = (bf16*)(ws + 80 * MB);         // 8 MiB
    bf16* w2b = (bf16*)(ws + 88 * MB);         // 8 MiB
    bf16* hb = (bf16*)(ws + 96 * MB);          // 64 MiB (GEMM phase)
    // attention-phase buffers alias hb's region (dead once gemm1 runs):
    short* xb = (short*)(ws + 96 * MB);        // 16 MiB bf16 x
    short* vt = (short*)(ws + 112 * MB);       // 16 MiB bf16 x^T per (b,h)
    float* y2 = attn_out;                      // reuse

    convert_bf16_kernel<<<4096, 256, 0, stream>>>(w1, w1b, F_ * D_);
    convert_bf16_kernel<<<4096, 256, 0, stream>>>(w2, w2b, D_ * F_);
    transpose_vt_kernel<<<dim3(B_ * H_, L_ / 64), 256, 0, stream>>>(x, vt, xb);

    flash_attn_kernel<<<B_ * H_ * (L_ / 128), 256, 0, stream>>>(x, xb, vt, attn_out);

    ln_kernel<<<B_ * L_, 256, 0, stream>>>(x, attn_out, g1, be1, x1, x1b);

    gemm_bt<0><<<dim3(F_ / 128, (B_ * L_) / 128), 256, 0, stream>>>(
        x1b, w1b, b1, nullptr, (void*)hb, B_ * L_, F_, D_);
    gemm_bt<2><<<dim3(D_ / 128, (B_ * L_) / 128), 256, 0, stream>>>(
        hb, w2b, b2, x1, (void*)y2, B_ * L_, D_, F_);

    ln_kernel<<<B_ * L_, 256, 0, stream>>>(y2, nullptr, g2, be2, out, nullptr);
}